// Round 10
// baseline (112.853 us; speedup 1.0000x reference)
//
#include <hip/hip_runtime.h>

#define N_NODES 10000
#define N_PAIRS 1200000
#define DIM 128
#define SEG_BLOCKS 4688    // ceil(N_PAIRS/256)
#define FW_BLOCKS 625      // 10000 rows / (4 waves * 4 rows)

typedef float f32x2 __attribute__((ext_vector_type(2)));   // NT-builtin-legal float2

__device__ inline float bf2f(unsigned short u) {
    return __uint_as_float(((unsigned int)u) << 16);
}
__device__ inline unsigned short f2bf(float f) {
    unsigned int i = __float_as_uint(f);
    return (unsigned short)((i + 0x7FFFu + ((i >> 16) & 1u)) >> 16);   // RNE
}
__device__ inline float rl_f(float v, int q) {
    return __uint_as_float(__builtin_amdgcn_readlane(__float_as_uint(v), q));
}

// ---------- Prep: blocks [0,SEG_BLOCKS) build seg[]; rest compute FW = F @ W (bf16). ----------
__global__ __launch_bounds__(256, 4)
void prep_kernel(const int* __restrict__ pair_node, int* __restrict__ seg,
                 const float* __restrict__ F, const float* __restrict__ W,
                 ushort2* __restrict__ FWb2)
{
    const int bid = blockIdx.x;
    if (bid < SEG_BLOCKS) {
        const int p = bid * 256 + threadIdx.x;
        if (p >= N_PAIRS) return;
        const int cur  = __builtin_nontemporal_load(&pair_node[p]);
        const int prev = (p == 0) ? -1 : __builtin_nontemporal_load(&pair_node[p - 1]);
        for (int n = prev + 1; n <= cur; ++n) seg[n] = p;
        if (p == N_PAIRS - 1)
            for (int n = cur + 1; n <= N_NODES; ++n) seg[n] = N_PAIRS;
        return;
    }

    // FW GEMM: wave per 4 rows, register-only. W (reused 2500x) stays cached; F is single-use.
    const int fb   = bid - SEG_BLOCKS;
    const int wid  = threadIdx.x >> 6;
    const int lane = threadIdx.x & 63;
    const int m0   = (fb * 4 + wid) * 4;
    if (m0 >= N_NODES) return;

    const f32x2* F2 = (const f32x2*)F;
    const f32x2* W2 = (const f32x2*)W;

    const f32x2 f0 = __builtin_nontemporal_load(&F2[(size_t)(m0 + 0) * 64 + lane]);
    const f32x2 f1 = __builtin_nontemporal_load(&F2[(size_t)(m0 + 1) * 64 + lane]);
    const f32x2 f2 = __builtin_nontemporal_load(&F2[(size_t)(m0 + 2) * 64 + lane]);
    const f32x2 f3 = __builtin_nontemporal_load(&F2[(size_t)(m0 + 3) * 64 + lane]);

    f32x2 a0 = {0.f, 0.f}, a1 = {0.f, 0.f}, a2 = {0.f, 0.f}, a3 = {0.f, 0.f};

    #pragma unroll 4
    for (int kk = 0; kk < 64; ++kk) {
        const f32x2 wa = W2[(size_t)(2 * kk + 0) * 64 + lane];
        const f32x2 wb = W2[(size_t)(2 * kk + 1) * 64 + lane];
        const float s0x = rl_f(f0.x, kk), s0y = rl_f(f0.y, kk);
        const float s1x = rl_f(f1.x, kk), s1y = rl_f(f1.y, kk);
        const float s2x = rl_f(f2.x, kk), s2y = rl_f(f2.y, kk);
        const float s3x = rl_f(f3.x, kk), s3y = rl_f(f3.y, kk);
        a0.x += s0x * wa.x + s0y * wb.x;  a0.y += s0x * wa.y + s0y * wb.y;
        a1.x += s1x * wa.x + s1y * wb.x;  a1.y += s1x * wa.y + s1y * wb.y;
        a2.x += s2x * wa.x + s2y * wb.x;  a2.y += s2x * wa.y + s2y * wb.y;
        a3.x += s3x * wa.x + s3y * wb.x;  a3.y += s3x * wa.y + s3y * wb.y;
    }

    ushort2 o;
    o.x = f2bf(a0.x); o.y = f2bf(a0.y); FWb2[(size_t)(m0 + 0) * 64 + lane] = o;
    o.x = f2bf(a1.x); o.y = f2bf(a1.y); FWb2[(size_t)(m0 + 1) * 64 + lane] = o;
    o.x = f2bf(a2.x); o.y = f2bf(a2.y); FWb2[(size_t)(m0 + 2) * 64 + lane] = o;
    o.x = f2bf(a3.x); o.y = f2bf(a3.y); FWb2[(size_t)(m0 + 3) * 64 + lane] = o;
}

// ---------- Fused: wave-per-node, barrier-free, LDS-free (round-5 structure). ----------
// Single-use streams (dist, pair_i/j/cos) are non-temporal so FW stays L2-resident.
__global__ __launch_bounds__(256, 8)
void fused_seg_kernel(const float* __restrict__ dist,
                      const ushort2* __restrict__ FW2,   // [N_NODES][64]
                      const int* __restrict__ seg,
                      const int* __restrict__ pair_i,
                      const int* __restrict__ pair_j,
                      const float* __restrict__ pair_cos,
                      const float* __restrict__ b,
                      float* __restrict__ out)
{
    const int wid  = threadIdx.x >> 6;
    const int lane = threadIdx.x & 63;
    const int n    = blockIdx.x * 4 + wid;     // grid = 2500 x 4 waves = 10000
    const int lo = seg[n];
    const int hi = seg[n + 1];
    const size_t drow = (size_t)n * N_NODES;

    float a0 = 0.f, a1 = 0.f;

    for (int base = lo; base < hi; base += 64) {
        // ---- phase A: this lane's pair weight (all streams non-temporal) ----
        const int p = base + lane;
        unsigned ijl = 0; float wl = 0.f;
        if (p < hi) {
            const int i = __builtin_nontemporal_load(&pair_i[p]);
            const int j = __builtin_nontemporal_load(&pair_j[p]);
            const float c  = __builtin_nontemporal_load(&pair_cos[p]);
            const float di = __builtin_nontemporal_load(&dist[drow + i]);
            const float dj = __builtin_nontemporal_load(&dist[drow + j]);
            ijl = ((unsigned)i << 14) | (unsigned)j;
            wl  = c * di * dj;
        }

        // ---- phase B: broadcast each pair, gather FW rows (L2-resident), accumulate ----
        const int qmax = min(64, hi - base);
        if (qmax == 64) {
            #pragma unroll 8
            for (int q = 0; q < 64; ++q) {
                const unsigned ijq = (unsigned)__builtin_amdgcn_readlane((int)ijl, q);
                const float    wq  = rl_f(wl, q);
                const int iq = (int)(ijq >> 14);
                const int jq = (int)(ijq & 16383u);
                const ushort2 fi = FW2[(size_t)iq * 64 + lane];
                const ushort2 fj = FW2[(size_t)jq * 64 + lane];
                a0 += wq * (bf2f(fi.x) + bf2f(fj.x));
                a1 += wq * (bf2f(fi.y) + bf2f(fj.y));
            }
        } else {
            #pragma unroll 4
            for (int q = 0; q < qmax; ++q) {
                const unsigned ijq = (unsigned)__builtin_amdgcn_readlane((int)ijl, q);
                const float    wq  = rl_f(wl, q);
                const int iq = (int)(ijq >> 14);
                const int jq = (int)(ijq & 16383u);
                const ushort2 fi = FW2[(size_t)iq * 64 + lane];
                const ushort2 fj = FW2[(size_t)jq * 64 + lane];
                a0 += wq * (bf2f(fi.x) + bf2f(fj.x));
                a1 += wq * (bf2f(fi.y) + bf2f(fj.y));
            }
        }
    }

    const float2 bb = ((const float2*)b)[lane];
    f32x2 o; o.x = a0 + bb.x; o.y = a1 + bb.y;
    __builtin_nontemporal_store(o, &((f32x2*)out)[(size_t)n * 64 + lane]);
}

extern "C" void kernel_launch(void* const* d_in, const int* in_sizes, int n_in,
                              void* d_out, int out_size, void* d_ws, size_t ws_size,
                              hipStream_t stream) {
    const float* features  = (const float*)d_in[0];
    const float* dist      = (const float*)d_in[1];
    const int*   pair_node = (const int*)  d_in[2];
    const int*   pair_i    = (const int*)  d_in[3];
    const int*   pair_j    = (const int*)  d_in[4];
    const float* pair_cos  = (const float*)d_in[5];
    const float* W         = (const float*)d_in[6];
    const float* b         = (const float*)d_in[7];
    float* out = (float*)d_out;

    // workspace: seg int[N_NODES+1] (padded to 40960 B), then FW bf16 (2.56 MB)
    int* seg = (int*)d_ws;
    ushort2* FWb2 = (ushort2*)((char*)d_ws + 10240 * sizeof(int));

    prep_kernel<<<SEG_BLOCKS + FW_BLOCKS, 256, 0, stream>>>(pair_node, seg, features, W, FWb2);
    fused_seg_kernel<<<N_NODES / 4, 256, 0, stream>>>(
        dist, FWb2, seg, pair_i, pair_j, pair_cos, b, out);
}

// Round 11
// 103.649 us; speedup vs baseline: 1.0888x; 1.0888x over previous
//
#include <hip/hip_runtime.h>

#define N_NODES 10000
#define N_PAIRS 1200000
#define DIM 128

__device__ inline float bf2f(unsigned short u) {
    return __uint_as_float(((unsigned int)u) << 16);
}
__device__ inline unsigned short f2bf(float f) {
    unsigned int i = __float_as_uint(f);
    unsigned int r = i + 0x7FFFu + ((i >> 16) & 1u);   // round-to-nearest-even
    return (unsigned short)(r >> 16);
}
__device__ inline float rl_f(float v, int q) {
    return __uint_as_float(__builtin_amdgcn_readlane(__float_as_uint(v), q));
}

// ---------- Kernel 0: segment starts. seg[n] = first pair index with node >= n. ----------
__global__ __launch_bounds__(256)
void seg_start_kernel(const int* __restrict__ pair_node, int* __restrict__ seg) {
    const int p = blockIdx.x * 256 + threadIdx.x;
    if (p >= N_PAIRS) return;
    const int cur  = pair_node[p];
    const int prev = (p == 0) ? -1 : pair_node[p - 1];
    for (int n = prev + 1; n <= cur; ++n) seg[n] = p;
    if (p == N_PAIRS - 1)
        for (int n = cur + 1; n <= N_NODES; ++n) seg[n] = N_PAIRS;
}

// ---------- Kernel A: FW = F @ W (bf16 out). Wave-per-4-rows, register-only. ----------
__global__ __launch_bounds__(256, 4)
void fw_gemm_kernel(const float* __restrict__ F, const float* __restrict__ W,
                    ushort2* __restrict__ FWb2)
{
    const int wid  = threadIdx.x >> 6;
    const int lane = threadIdx.x & 63;
    const int m0   = (blockIdx.x * 4 + wid) * 4;       // 4 rows per wave
    if (m0 >= N_NODES) return;

    const float2* F2 = (const float2*)F;
    const float2* W2 = (const float2*)W;

    // lane holds k = {2*lane, 2*lane+1} of each F row
    const float2 f0 = F2[(size_t)(m0 + 0) * 64 + lane];
    const float2 f1 = F2[(size_t)(m0 + 1) * 64 + lane];
    const float2 f2 = F2[(size_t)(m0 + 2) * 64 + lane];
    const float2 f3 = F2[(size_t)(m0 + 3) * 64 + lane];

    float2 a0 = {0.f, 0.f}, a1 = {0.f, 0.f}, a2 = {0.f, 0.f}, a3 = {0.f, 0.f};

    #pragma unroll 4
    for (int kk = 0; kk < 64; ++kk) {
        // W rows k=2kk and k=2kk+1, lane covers dims {2*lane, 2*lane+1}
        const float2 wa = W2[(size_t)(2 * kk + 0) * 64 + lane];
        const float2 wb = W2[(size_t)(2 * kk + 1) * 64 + lane];
        const float s0x = rl_f(f0.x, kk), s0y = rl_f(f0.y, kk);
        const float s1x = rl_f(f1.x, kk), s1y = rl_f(f1.y, kk);
        const float s2x = rl_f(f2.x, kk), s2y = rl_f(f2.y, kk);
        const float s3x = rl_f(f3.x, kk), s3y = rl_f(f3.y, kk);
        a0.x += s0x * wa.x + s0y * wb.x;  a0.y += s0x * wa.y + s0y * wb.y;
        a1.x += s1x * wa.x + s1y * wb.x;  a1.y += s1x * wa.y + s1y * wb.y;
        a2.x += s2x * wa.x + s2y * wb.x;  a2.y += s2x * wa.y + s2y * wb.y;
        a3.x += s3x * wa.x + s3y * wb.x;  a3.y += s3x * wa.y + s3y * wb.y;
    }

    ushort2 o;
    o.x = f2bf(a0.x); o.y = f2bf(a0.y); FWb2[(size_t)(m0 + 0) * 64 + lane] = o;
    o.x = f2bf(a1.x); o.y = f2bf(a1.y); FWb2[(size_t)(m0 + 1) * 64 + lane] = o;
    o.x = f2bf(a2.x); o.y = f2bf(a2.y); FWb2[(size_t)(m0 + 2) * 64 + lane] = o;
    o.x = f2bf(a3.x); o.y = f2bf(a3.y); FWb2[(size_t)(m0 + 3) * 64 + lane] = o;
}

// ---------- Fused: wave-per-node, barrier-free, LDS-free ----------
// Phase A (per 64-pair chunk): lane l computes w for pair base+l (2 dist gathers,
// row-local burst). Phase B: loop q over chunk; readlane-broadcast (i,j,w) -> SGPRs;
// each lane accumulates dims {2*lane, 2*lane+1} from ushort2 FW rows (L2-resident).
__global__ __launch_bounds__(256, 8)
void fused_seg_kernel(const float* __restrict__ dist,
                      const ushort2* __restrict__ FW2,   // [N_NODES][64]
                      const int* __restrict__ seg,
                      const int* __restrict__ pair_i,
                      const int* __restrict__ pair_j,
                      const float* __restrict__ pair_cos,
                      const float* __restrict__ b,
                      float* __restrict__ out)
{
    const int wid  = threadIdx.x >> 6;
    const int lane = threadIdx.x & 63;
    const int n    = blockIdx.x * 4 + wid;     // grid = 2500 x 4 waves = 10000
    const int lo = seg[n];
    const int hi = seg[n + 1];
    const size_t drow = (size_t)n * N_NODES;

    float a0 = 0.f, a1 = 0.f;

    for (int base = lo; base < hi; base += 64) {
        // ---- phase A: this lane's pair weight ----
        const int p = base + lane;
        int il = 0, jl = 0; float wl = 0.f;
        if (p < hi) {
            il = pair_i[p];
            jl = pair_j[p];
            wl = pair_cos[p] * dist[drow + il] * dist[drow + jl];
        }

        // ---- phase B: broadcast each pair, gather FW rows, accumulate ----
        const int qmax = min(64, hi - base);
        if (qmax == 64) {
            #pragma unroll 8
            for (int q = 0; q < 64; ++q) {
                const int   iq = __builtin_amdgcn_readlane(il, q);
                const int   jq = __builtin_amdgcn_readlane(jl, q);
                const float wq = rl_f(wl, q);
                const ushort2 fi = FW2[(size_t)iq * 64 + lane];
                const ushort2 fj = FW2[(size_t)jq * 64 + lane];
                a0 += wq * (bf2f(fi.x) + bf2f(fj.x));
                a1 += wq * (bf2f(fi.y) + bf2f(fj.y));
            }
        } else {
            #pragma unroll 4
            for (int q = 0; q < qmax; ++q) {
                const int   iq = __builtin_amdgcn_readlane(il, q);
                const int   jq = __builtin_amdgcn_readlane(jl, q);
                const float wq = rl_f(wl, q);
                const ushort2 fi = FW2[(size_t)iq * 64 + lane];
                const ushort2 fj = FW2[(size_t)jq * 64 + lane];
                a0 += wq * (bf2f(fi.x) + bf2f(fj.x));
                a1 += wq * (bf2f(fi.y) + bf2f(fj.y));
            }
        }
    }

    const float2 bb = ((const float2*)b)[lane];
    float2 o; o.x = a0 + bb.x; o.y = a1 + bb.y;
    ((float2*)out)[(size_t)n * 64 + lane] = o;
}

extern "C" void kernel_launch(void* const* d_in, const int* in_sizes, int n_in,
                              void* d_out, int out_size, void* d_ws, size_t ws_size,
                              hipStream_t stream) {
    const float* features  = (const float*)d_in[0];
    const float* dist      = (const float*)d_in[1];
    const int*   pair_node = (const int*)  d_in[2];
    const int*   pair_i    = (const int*)  d_in[3];
    const int*   pair_j    = (const int*)  d_in[4];
    const float* pair_cos  = (const float*)d_in[5];
    const float* W         = (const float*)d_in[6];
    const float* b         = (const float*)d_in[7];
    float* out = (float*)d_out;

    // workspace: seg int[N_NODES+1] (padded to 40960B), then FWb bf16 (2.56 MB)
    int* seg = (int*)d_ws;
    ushort2* FWb2 = (ushort2*)((char*)d_ws + 10240 * sizeof(int));

    seg_start_kernel<<<(N_PAIRS + 255) / 256, 256, 0, stream>>>(pair_node, seg);
    fw_gemm_kernel<<<N_NODES / 16, 256, 0, stream>>>(features, W, FWb2);
    fused_seg_kernel<<<N_NODES / 4, 256, 0, stream>>>(
        dist, FWb2, seg, pair_i, pair_j, pair_cos, b, out);
}